// Round 5
// baseline (72.244 us; speedup 1.0000x reference)
//
#include <hip/hip_runtime.h>
#include <cstdint>

// CovNet BNN: out = clip(x @ sign(W1)^T + b1, ±1) @ W2^T + b2
// B=8192, IN=784, HID=4096, OUT=10.
// R5: LDS-traffic fix. R2-R4 were LDS-read-BW-bound (393 KB/block/K-tile =
// 4624 cyc > MFMA 2483). Changes:
//  - mfma_f32_32x32x16_f16 (16 FLOP per LDS byte vs 8)
//  - phase = k-step: read af[4]+bf[2] once, 8 MFMAs, no fragment re-reads
//    -> 192 KB/block/K-tile (~2258 cyc) ~ MFMA floor (2066 cyc)
//  - full-tile prefetch at s=0 into buf p^1 (8 gl_lds), counted vmcnt(8),
//    2 barriers/K-tile: s0 (tile ready), s3 after lgkmcnt(0) (reads drained
//    -> next tile may stage into buf p)
// Frag layouts (32x32x16 f16): A[row=l&31][k=(l>>5)*8+j]; B same by symmetry;
// C/D: col=l&31, row=(r&3)+8*(r>>2)+4*(l>>5)  [m74/m101 verified].

#define BATCH 8192
#define IN_F  784
#define HID   4096
#define OUT_F 10
#define KP    832     // padded K = 13*64
#define NKT   13
#define BM    256
#define BN    256
#define BK    64
#define NCT   (HID / BN)   // 16 col tiles
#define HCS   264          // epilogue hc row stride (f16)

typedef unsigned short u16;
typedef __attribute__((ext_vector_type(4))) unsigned short u16x4;
typedef __attribute__((ext_vector_type(8)))  _Float16 f16x8;
typedef __attribute__((ext_vector_type(4)))  float    f32x4;
typedef __attribute__((ext_vector_type(16))) float    f32x16;

#define BARRIER() do { asm volatile("" ::: "memory"); \
                       __builtin_amdgcn_s_barrier();  \
                       asm volatile("" ::: "memory"); } while (0)
#define WAITV(n)  asm volatile("s_waitcnt vmcnt(" #n ")" ::: "memory")

__device__ __forceinline__ u16 f2h(float f) {
  union { _Float16 h; u16 u; } c;
  c.h = (_Float16)f;   // RNE
  return c.u;
}

__device__ __forceinline__ void gl_lds16(const void* g, void* l) {
  __builtin_amdgcn_global_load_lds(
      (const __attribute__((address_space(1))) uint32_t*)g,
      (__attribute__((address_space(3))) uint32_t*)l, 16, 0, 0);
}

// ---------------- prep: x -> f16 (padded), W1 -> sign f16 (padded), W2 -> [16][4096]
__global__ void prep_kernel(const float* __restrict__ x, const float* __restrict__ W1,
                            const float* __restrict__ W2,
                            u16* __restrict__ xh, u16* __restrict__ wh,
                            u16* __restrict__ w2h) {
  const int stride = gridDim.x * blockDim.x;
  const int gid = blockIdx.x * blockDim.x + threadIdx.x;
  const int KP4 = KP / 4;    // 208
  const int IN4 = IN_F / 4;  // 196
  const float4* x4 = (const float4*)x;
  const float4* w4 = (const float4*)W1;
  for (int i = gid; i < BATCH * KP4; i += stride) {
    int b = i / KP4, k = i - b * KP4;
    u16x4 o = {0, 0, 0, 0};
    if (k < IN4) {
      float4 v = x4[(size_t)b * IN4 + k];
      o[0] = f2h(v.x); o[1] = f2h(v.y); o[2] = f2h(v.z); o[3] = f2h(v.w);
    }
    *(u16x4*)&xh[(size_t)b * KP + k * 4] = o;
  }
  for (int i = gid; i < HID * KP4; i += stride) {
    int h = i / KP4, k = i - h * KP4;
    u16x4 o = {0, 0, 0, 0};
    if (k < IN4) {
      float4 v = w4[(size_t)h * IN4 + k];
      o[0] = v.x > 0.f ? 0x3C00 : (v.x < 0.f ? 0xBC00 : 0);
      o[1] = v.y > 0.f ? 0x3C00 : (v.y < 0.f ? 0xBC00 : 0);
      o[2] = v.z > 0.f ? 0x3C00 : (v.z < 0.f ? 0xBC00 : 0);
      o[3] = v.w > 0.f ? 0x3C00 : (v.w < 0.f ? 0xBC00 : 0);
    }
    *(u16x4*)&wh[(size_t)h * KP + k * 4] = o;
  }
  for (int i = gid; i < 16 * HID; i += stride) {
    int o = i >> 12, k = i & (HID - 1);
    w2h[i] = (o < OUT_F) ? f2h(W2[o * HID + k]) : (u16)0;
  }
}

// ---------------- main fused GEMM (256x256, 8 waves, 32x32x16, k-step phases)
__global__ void __launch_bounds__(512, 2) gemm_kernel(
    const u16* __restrict__ xh, const u16* __restrict__ wh,
    const u16* __restrict__ w2h, const float* __restrict__ b1,
    float* __restrict__ part) {
  __shared__ union {
    struct { u16 A[2][BM * BK]; u16 B[2][BN * BK]; } m;   // 128 KiB
    struct { u16 hc[128 * HCS]; u16 w2[16 * 256]; } e;    // ~74 KiB
  } sm;

  const int t   = threadIdx.x;
  const int ct  = blockIdx.x;   // col tile (HID), 0..15
  const int br  = blockIdx.y;   // row tile (BATCH), 0..31
  const int w   = t >> 6;       // wave 0..7
  const int l   = t & 63;
  const int wm  = w >> 2;       // 0..1: wave rows = mi*64 + wm*32
  const int wn  = w & 3;        // 0..3: wave cols = nh*128 + wn*32
  const int lo  = l & 31;
  const int hi  = l >> 5;
  const int g   = l >> 4;       // for 16x16 epilogue GEMM2
  const int r16 = l & 15;

  // staging: thread t covers 16B; per 64-row chunk: row = t>>3; source slot
  // pre-swizzled (rule #21): logical slot = (t&7)^(row&7); LDS dest linear.
  const int  srow  = t >> 3;
  const int  sslot = (t & 7) ^ (srow & 7);
  const u16* gA = xh + (size_t)(br * BM) * KP + sslot * 8;
  const u16* gB = wh + (size_t)(ct * BN) * KP + sslot * 8;

  auto stage = [&](int tile) {   // full tile -> buf tile&1 (8 gl_lds/thread)
    const int b = tile & 1;
#pragma unroll
    for (int c = 0; c < 4; ++c)
      gl_lds16(gA + (size_t)(c * 64 + srow) * KP + tile * BK,
               &sm.m.A[b][c * 4096 + t * 8]);
#pragma unroll
    for (int c = 0; c < 4; ++c)
      gl_lds16(gB + (size_t)(c * 64 + srow) * KP + tile * BK,
               &sm.m.B[b][c * 4096 + t * 8]);
  };
  // read with the same XOR involution: phys slot = logical slot ^ (row&7)
  auto rdA = [&](int p, int mi, int s) -> f16x8 {
    int row = mi * 64 + wm * 32 + lo;
    return *(const f16x8*)&sm.m.A[p][row * 64 + (((s * 2 + hi) ^ (row & 7)) << 3)];
  };
  auto rdB = [&](int p, int nh, int s) -> f16x8 {
    int row = nh * 128 + wn * 32 + lo;
    return *(const f16x8*)&sm.m.B[p][row * 64 + (((s * 2 + hi) ^ (row & 7)) << 3)];
  };

  f32x16 acc[4][2] = {};   // [mi][nh], 128 VGPRs

  stage(0);   // prologue: tile 0 in flight (8 ops)

  for (int tt = 0; tt < NKT; ++tt) {
    const int p = tt & 1;
#pragma unroll
    for (int s = 0; s < 4; ++s) {
      if (s == 0) {
        if (tt + 1 < NKT) { stage(tt + 1); WAITV(8); }   // tile tt landed
        else              { WAITV(0); }                  // tail drain
        BARRIER();
      }
      f16x8 af[4], bf[2];
#pragma unroll
      for (int nh = 0; nh < 2; ++nh) bf[nh] = rdB(p, nh, s);
#pragma unroll
      for (int mi = 0; mi < 4; ++mi) af[mi] = rdA(p, mi, s);
      if (s == 3) {
        // all this wave's reads of buf p issued & complete -> after the
        // barrier, q0(t+1) may stage into buf p under our feet safely.
        asm volatile("s_waitcnt lgkmcnt(0)" ::: "memory");
        __builtin_amdgcn_sched_barrier(0);
        BARRIER();
      }
      __builtin_amdgcn_s_setprio(1);
#pragma unroll
      for (int mi = 0; mi < 4; ++mi)
#pragma unroll
        for (int nh = 0; nh < 2; ++nh)
          acc[mi][nh] = __builtin_amdgcn_mfma_f32_32x32x16_f16(af[mi], bf[nh], acc[mi][nh], 0, 0, 0);
      __builtin_amdgcn_s_setprio(0);
    }
  }

  // ---- epilogue: h = clip(acc + b1), fused GEMM2 through LDS ----
  // (all main-loop vmem drained: tile 12 s0 waited vmcnt(0))
  {
    int row = t >> 5, sp = t & 31;
    int ls = (sp & 24) | ((sp ^ row) & 7);   // swizzled logical slot
    gl_lds16(w2h + (size_t)row * HID + ct * BN + ls * 8, &sm.e.w2[t * 8]);
  }
  float b1v[2];
#pragma unroll
  for (int nh = 0; nh < 2; ++nh) b1v[nh] = b1[ct * BN + nh * 128 + wn * 32 + lo];

  float* partBase = part + ((size_t)ct * BATCH + br * BM) * 16;

#pragma unroll
  for (int p = 0; p < 2; ++p) {
    if (p == 1) BARRIER();               // p=0 hc reads done before overwrite
    // pass p writes global rows [p*128, p*128+128) = acc[p*2 + mi'][*]
    // local hc row = mi'*64 + wm*32 + crow;  crow = (r&3)+8*(r>>2)+4*hi
#pragma unroll
    for (int mi = 0; mi < 2; ++mi)
#pragma unroll
      for (int nh = 0; nh < 2; ++nh)
#pragma unroll
        for (int r = 0; r < 16; ++r) {
          float v = acc[p * 2 + mi][nh][r] + b1v[nh];
          v = fminf(fmaxf(v, -1.f), 1.f);
          int crow = (r & 3) + 8 * (r >> 2) + 4 * hi;
          sm.e.hc[(mi * 64 + wm * 32 + crow) * HCS + nh * 128 + wn * 32 + lo] = f2h(v);
        }
    if (p == 0) { WAITV(0); }            // w2 landed
    BARRIER();
    f32x4 acc2 = {};
#pragma unroll
    for (int kk = 0; kk < 8; ++kk) {
      f16x8 a2 = *(const f16x8*)&sm.e.hc[(w * 16 + r16) * HCS + kk * 32 + g * 8];
      int s   = kk * 4 + g;
      int sp2 = (s & 24) | ((s ^ r16) & 7);
      f16x8 b2f = *(const f16x8*)&sm.e.w2[r16 * 256 + sp2 * 8];
      acc2 = __builtin_amdgcn_mfma_f32_16x16x32_f16(a2, b2f, acc2, 0, 0, 0);
    }
#pragma unroll
    for (int r = 0; r < 4; ++r)
      partBase[(size_t)(p * 128 + w * 16 + g * 4 + r) * 16 + r16] = acc2[r];
  }
}

// ---------------- reduce partials over 16 col tiles + b2
__global__ void reduce_kernel(const float* __restrict__ part, const float* __restrict__ b2,
                              float* __restrict__ out) {
  int i = blockIdx.x * blockDim.x + threadIdx.x;
  if (i >= BATCH * OUT_F) return;
  int b = i / OUT_F, o = i - b * OUT_F;
  float acc = b2[o];
#pragma unroll
  for (int c = 0; c < NCT; ++c)
    acc += part[((size_t)c * BATCH + b) * 16 + o];
  out[i] = acc;
}

extern "C" void kernel_launch(void* const* d_in, const int* in_sizes, int n_in,
                              void* d_out, int out_size, void* d_ws, size_t ws_size,
                              hipStream_t stream) {
  const float* x  = (const float*)d_in[0];
  const float* W1 = (const float*)d_in[1];
  const float* b1 = (const float*)d_in[2];
  const float* W2 = (const float*)d_in[3];
  const float* b2 = (const float*)d_in[4];
  float* out = (float*)d_out;

  // ws layout (~29 MB): xh 13.6 MB | wh 6.8 MB | w2h 0.13 MB | part 8.4 MB
  u16* xh  = (u16*)d_ws;
  u16* wh  = xh + (size_t)BATCH * KP;
  u16* w2h = wh + (size_t)HID * KP;
  float* part = (float*)(w2h + 16 * HID);

  hipLaunchKernelGGL(prep_kernel, dim3(2048), dim3(256), 0, stream, x, W1, W2, xh, wh, w2h);
  hipLaunchKernelGGL(gemm_kernel, dim3(NCT, BATCH / BM), dim3(512), 0, stream,
                     xh, wh, w2h, b1, part);
  hipLaunchKernelGGL(reduce_kernel, dim3((BATCH * OUT_F + 255) / 256), dim3(256), 0, stream,
                     part, b2, out);
}

// Round 6
// 67.257 us; speedup vs baseline: 1.0742x; 1.0742x over previous
//
#include <hip/hip_runtime.h>
#include <cstdint>

// CovNet BNN: out = clip(x @ sign(W1)^T + b1, ±1) @ W2^T + b2
// B=8192, IN=784, HID=4096, OUT=10.
// R6: 32x32x16 (R5 layouts, verified) + fragment software-pipeline:
// per kk-phase issue next-kk's 6 ds_read into the alternate frag set, then
// run 8 MFMAs on the current set (no dep on in-flight reads). ONE barrier +
// lgkmcnt(0) + vmcnt(0) per K-tile (at kk3). Waves free-run within a tile.
// Race audit:
//  - stage(t+1)->p^1 issued at kk0; reads of p^1 only after kk3's
//    [per-wave vmcnt(0)] + barrier => all waves' stages landed. OK
//  - stage(t+2)->p issued at t+1 kk0, after the kk3 barrier; every wave's
//    reads of p completed before its barrier arrival (lgkmcnt(0)). OK
//  - kk3 MFMA runs post-barrier on REGISTERS only (frags read at kk2). OK
//  - epilogue: explicit lgkmcnt(0)+barrier after loop (tile 12 ends
//    barrier-less; w2/hc writes alias A[0]/B[0] in the union). OK

#define BATCH 8192
#define IN_F  784
#define HID   4096
#define OUT_F 10
#define KP    832     // padded K = 13*64
#define NKT   13
#define BM    256
#define BN    256
#define BK    64
#define NCT   (HID / BN)   // 16 col tiles
#define HCS   264          // epilogue hc row stride (f16)

typedef unsigned short u16;
typedef __attribute__((ext_vector_type(4))) unsigned short u16x4;
typedef __attribute__((ext_vector_type(8)))  _Float16 f16x8;
typedef __attribute__((ext_vector_type(4)))  float    f32x4;
typedef __attribute__((ext_vector_type(16))) float    f32x16;

#define BARRIER() do { asm volatile("" ::: "memory"); \
                       __builtin_amdgcn_s_barrier();  \
                       asm volatile("" ::: "memory"); } while (0)
#define WAITV(n)  asm volatile("s_waitcnt vmcnt(" #n ")" ::: "memory")
#define WAITL0()  asm volatile("s_waitcnt lgkmcnt(0)" ::: "memory")

__device__ __forceinline__ u16 f2h(float f) {
  union { _Float16 h; u16 u; } c;
  c.h = (_Float16)f;   // RNE
  return c.u;
}

__device__ __forceinline__ void gl_lds16(const void* g, void* l) {
  __builtin_amdgcn_global_load_lds(
      (const __attribute__((address_space(1))) uint32_t*)g,
      (__attribute__((address_space(3))) uint32_t*)l, 16, 0, 0);
}

// ---------------- prep: x -> f16 (padded), W1 -> sign f16 (padded), W2 -> [16][4096]
__global__ void prep_kernel(const float* __restrict__ x, const float* __restrict__ W1,
                            const float* __restrict__ W2,
                            u16* __restrict__ xh, u16* __restrict__ wh,
                            u16* __restrict__ w2h) {
  const int stride = gridDim.x * blockDim.x;
  const int gid = blockIdx.x * blockDim.x + threadIdx.x;
  const int KP4 = KP / 4;    // 208
  const int IN4 = IN_F / 4;  // 196
  const float4* x4 = (const float4*)x;
  const float4* w4 = (const float4*)W1;
  for (int i = gid; i < BATCH * KP4; i += stride) {
    int b = i / KP4, k = i - b * KP4;
    u16x4 o = {0, 0, 0, 0};
    if (k < IN4) {
      float4 v = x4[(size_t)b * IN4 + k];
      o[0] = f2h(v.x); o[1] = f2h(v.y); o[2] = f2h(v.z); o[3] = f2h(v.w);
    }
    *(u16x4*)&xh[(size_t)b * KP + k * 4] = o;
  }
  for (int i = gid; i < HID * KP4; i += stride) {
    int h = i / KP4, k = i - h * KP4;
    u16x4 o = {0, 0, 0, 0};
    if (k < IN4) {
      float4 v = w4[(size_t)h * IN4 + k];
      o[0] = v.x > 0.f ? 0x3C00 : (v.x < 0.f ? 0xBC00 : 0);
      o[1] = v.y > 0.f ? 0x3C00 : (v.y < 0.f ? 0xBC00 : 0);
      o[2] = v.z > 0.f ? 0x3C00 : (v.z < 0.f ? 0xBC00 : 0);
      o[3] = v.w > 0.f ? 0x3C00 : (v.w < 0.f ? 0xBC00 : 0);
    }
    *(u16x4*)&wh[(size_t)h * KP + k * 4] = o;
  }
  for (int i = gid; i < 16 * HID; i += stride) {
    int o = i >> 12, k = i & (HID - 1);
    w2h[i] = (o < OUT_F) ? f2h(W2[o * HID + k]) : (u16)0;
  }
}

// ---------------- main fused GEMM (256x256, 8 waves, 32x32x16, frag pipeline)
__global__ void __launch_bounds__(512, 2) gemm_kernel(
    const u16* __restrict__ xh, const u16* __restrict__ wh,
    const u16* __restrict__ w2h, const float* __restrict__ b1,
    float* __restrict__ part) {
  __shared__ union {
    struct { u16 A[2][BM * BK]; u16 B[2][BN * BK]; } m;   // 128 KiB
    struct { u16 hc[128 * HCS]; u16 w2[16 * 256]; } e;    // ~74 KiB
  } sm;

  const int t   = threadIdx.x;
  const int ct  = blockIdx.x;   // col tile (HID), 0..15
  const int br  = blockIdx.y;   // row tile (BATCH), 0..31
  const int w   = t >> 6;       // wave 0..7
  const int l   = t & 63;
  const int wm  = w >> 2;       // 0..1: wave rows = mi*64 + wm*32
  const int wn  = w & 3;        // 0..3: wave cols = nh*128 + wn*32
  const int lo  = l & 31;
  const int hi  = l >> 5;
  const int g   = l >> 4;       // for 16x16 epilogue GEMM2
  const int r16 = l & 15;

  // staging: thread t covers 16B; per 64-row chunk: row = t>>3; source slot
  // pre-swizzled (rule #21): logical slot = (t&7)^(row&7); LDS dest linear.
  const int  srow  = t >> 3;
  const int  sslot = (t & 7) ^ (srow & 7);
  const u16* gA = xh + (size_t)(br * BM) * KP + sslot * 8;
  const u16* gB = wh + (size_t)(ct * BN) * KP + sslot * 8;

  auto stage = [&](int tile) {   // full tile -> buf tile&1 (8 gl_lds/thread)
    const int b = tile & 1;
#pragma unroll
    for (int c = 0; c < 4; ++c)
      gl_lds16(gA + (size_t)(c * 64 + srow) * KP + tile * BK,
               &sm.m.A[b][c * 4096 + t * 8]);
#pragma unroll
    for (int c = 0; c < 4; ++c)
      gl_lds16(gB + (size_t)(c * 64 + srow) * KP + tile * BK,
               &sm.m.B[b][c * 4096 + t * 8]);
  };
  // read with the same XOR involution: phys slot = logical slot ^ (row&7)
  auto rdA = [&](int p, int mi, int kk) -> f16x8 {
    int row = mi * 64 + wm * 32 + lo;
    return *(const f16x8*)&sm.m.A[p][row * 64 + (((kk * 2 + hi) ^ (row & 7)) << 3)];
  };
  auto rdB = [&](int p, int nh, int kk) -> f16x8 {
    int row = nh * 128 + wn * 32 + lo;
    return *(const f16x8*)&sm.m.B[p][row * 64 + (((kk * 2 + hi) ^ (row & 7)) << 3)];
  };

  f32x16 acc[4][2] = {};   // [mi][nh] in AGPRs
  f16x8 af[2][4], bf[2][2];   // two named frag sets, static indices only

#define RD(S, P, KK) do {                                             \
    _Pragma("unroll") for (int mi_ = 0; mi_ < 4; ++mi_) af[S][mi_] = rdA(P, mi_, KK); \
    _Pragma("unroll") for (int nh_ = 0; nh_ < 2; ++nh_) bf[S][nh_] = rdB(P, nh_, KK); \
  } while (0)
#define MFMA8(S) do {                                                 \
    __builtin_amdgcn_s_setprio(1);                                    \
    _Pragma("unroll") for (int mi_ = 0; mi_ < 4; ++mi_)               \
      _Pragma("unroll") for (int nh_ = 0; nh_ < 2; ++nh_)             \
        acc[mi_][nh_] = __builtin_amdgcn_mfma_f32_32x32x16_f16(       \
            af[S][mi_], bf[S][nh_], acc[mi_][nh_], 0, 0, 0);          \
    __builtin_amdgcn_s_setprio(0);                                    \
  } while (0)

  // prologue
  stage(0);
  WAITV(0);
  BARRIER();
  RD(0, 0, 0);

  for (int tt = 0; tt < NKT; ++tt) {
    const int  p    = tt & 1;
    const bool more = (tt + 1 < NKT);
    if (more) stage(tt + 1);   // 8 gl_lds -> buf p^1
    RD(1, p, 1);  MFMA8(0);    // kk0
    RD(0, p, 2);  MFMA8(1);    // kk1
    RD(1, p, 3);  MFMA8(0);    // kk2
    if (more) {                // kk3
      WAITL0();                // my reads of buf p done (incl. set1/kk3)
      WAITV(0);                // my 8 stage loads for t+1 landed
      BARRIER();               // => p^1 fully staged; everyone's p-reads done
      RD(0, p ^ 1, 0);         // prefetch kk0 of t+1
    }
    MFMA8(1);                  // kk3 (registers only)
  }

  // ---- epilogue: h = clip(acc + b1), fused GEMM2 through LDS ----
  WAITL0();
  BARRIER();   // tile 12 ended barrier-less; e.* aliases m.A[0]/m.B[0]
  {
    int row = t >> 5, sp = t & 31;
    int ls = (sp & 24) | ((sp ^ row) & 7);   // swizzled logical slot
    gl_lds16(w2h + (size_t)row * HID + ct * BN + ls * 8, &sm.e.w2[t * 8]);
  }
  float b1v[2];
#pragma unroll
  for (int nh = 0; nh < 2; ++nh) b1v[nh] = b1[ct * BN + nh * 128 + wn * 32 + lo];

  float* partBase = part + ((size_t)ct * BATCH + br * BM) * 16;

#pragma unroll
  for (int p = 0; p < 2; ++p) {
    if (p == 1) BARRIER();               // p=0 hc reads done before overwrite
    // pass p writes global rows [p*128, p*128+128) = acc[p*2 + mi'][*]
    // local hc row = mi'*64 + wm*32 + crow;  crow = (r&3)+8*(r>>2)+4*hi
#pragma unroll
    for (int mi = 0; mi < 2; ++mi)
#pragma unroll
      for (int nh = 0; nh < 2; ++nh)
#pragma unroll
        for (int r = 0; r < 16; ++r) {
          float v = acc[p * 2 + mi][nh][r] + b1v[nh];
          v = fminf(fmaxf(v, -1.f), 1.f);
          int crow = (r & 3) + 8 * (r >> 2) + 4 * hi;
          sm.e.hc[(mi * 64 + wm * 32 + crow) * HCS + nh * 128 + wn * 32 + lo] = f2h(v);
        }
    if (p == 0) { WAITV(0); }            // w2 landed
    BARRIER();
    f32x4 acc2 = {};
#pragma unroll
    for (int kk = 0; kk < 8; ++kk) {
      f16x8 a2 = *(const f16x8*)&sm.e.hc[(w * 16 + r16) * HCS + kk * 32 + g * 8];
      int s   = kk * 4 + g;
      int sp2 = (s & 24) | ((s ^ r16) & 7);
      f16x8 b2f = *(const f16x8*)&sm.e.w2[r16 * 256 + sp2 * 8];
      acc2 = __builtin_amdgcn_mfma_f32_16x16x32_f16(a2, b2f, acc2, 0, 0, 0);
    }
#pragma unroll
    for (int r = 0; r < 4; ++r)
      partBase[(size_t)(p * 128 + w * 16 + g * 4 + r) * 16 + r16] = acc2[r];
  }
}

// ---------------- reduce partials over 16 col tiles + b2
__global__ void reduce_kernel(const float* __restrict__ part, const float* __restrict__ b2,
                              float* __restrict__ out) {
  int i = blockIdx.x * blockDim.x + threadIdx.x;
  if (i >= BATCH * OUT_F) return;
  int b = i / OUT_F, o = i - b * OUT_F;
  float acc = b2[o];
#pragma unroll
  for (int c = 0; c < NCT; ++c)
    acc += part[((size_t)c * BATCH + b) * 16 + o];
  out[i] = acc;
}

extern "C" void kernel_launch(void* const* d_in, const int* in_sizes, int n_in,
                              void* d_out, int out_size, void* d_ws, size_t ws_size,
                              hipStream_t stream) {
  const float* x  = (const float*)d_in[0];
  const float* W1 = (const float*)d_in[1];
  const float* b1 = (const float*)d_in[2];
  const float* W2 = (const float*)d_in[3];
  const float* b2 = (const float*)d_in[4];
  float* out = (float*)d_out;

  // ws layout (~29 MB): xh 13.6 MB | wh 6.8 MB | w2h 0.13 MB | part 8.4 MB
  u16* xh  = (u16*)d_ws;
  u16* wh  = xh + (size_t)BATCH * KP;
  u16* w2h = wh + (size_t)HID * KP;
  float* part = (float*)(w2h + 16 * HID);

  hipLaunchKernelGGL(prep_kernel, dim3(2048), dim3(256), 0, stream, x, W1, W2, xh, wh, w2h);
  hipLaunchKernelGGL(gemm_kernel, dim3(NCT, BATCH / BM), dim3(512), 0, stream,
                     xh, wh, w2h, b1, part);
  hipLaunchKernelGGL(reduce_kernel, dim3((BATCH * OUT_F + 255) / 256), dim3(256), 0, stream,
                     part, b2, out);
}